// Round 3
// baseline (147.912 us; speedup 1.0000x reference)
//
#include <hip/hip_runtime.h>

// SystemsOfSprings, round 2: per-node threads + DPP quad_perm neighbors +
// rsq-based edge force + 4 elements/thread for memory-level parallelism.
//
// R1 was latency-bound (2.79 TB/s, VALUBusy 34%, occupancy 64%, nothing
// saturated): critical path = load -> 6x ds_bpermute (LDS pipe round-trips)
// -> 3x precise sqrt + 3x IEEE div sequences -> store, with 1 element/thread.
// This round:
//   * __shfl_xor(.,d,4) -> v_mov_b32_dpp quad_perm (VALU, no waitcnt):
//       xor1 = [1,0,3,2] = 0xB1, xor2 = [2,3,0,1] = 0x4E, xor3 = [3,2,1,0] = 0x1B
//   * edge force algebra: (r-L)*(d/r) = d*(1 - L*rsq(d2)) -> one v_rsq_f32,
//     no divide, no sqrt. d2==0 keeps the reference's atan2(0,0)=0 convention
//     via one cndmask per component (contribution = -L on x, 0 on y).
//   * 4 elements per thread, block-linear (elem e of thread t at
//     blockIdx*1024 + e*256 + t) -> 8 independent outstanding loads/thread.

#define TS 0.05f
#define NELEM 4

template<int CTRL>
__device__ __forceinline__ float qp(float v) {
    // quad_perm DPP: row_mask=0xF, bank_mask=0xF, bound_ctrl=1
    return __int_as_float(__builtin_amdgcn_update_dpp(
        0, __float_as_int(v), CTRL, 0xF, 0xF, true));
}

__device__ __forceinline__ void edge(float px, float py, float qx, float qy,
                                     float L, float& ax, float& ay) {
    float dx = px - qx;
    float dy = py - qy;
    float d2 = fmaf(dx, dx, dy * dy);
    float invr = __builtin_amdgcn_rsqf(d2);     // inf when d2==0
    float s = fmaf(-L, invr, 1.0f);             // (r - L) / r
    bool nz = d2 > 0.f;
    float fx = nz ? dx * s : -L;                // r==0: c=1,s=0 convention
    float fy = nz ? dy * s : 0.f;
    ax -= fx;
    ay -= fy;
}

__global__ __launch_bounds__(256) void springs_node_kernel(
    const float* __restrict__ x,
    const float* __restrict__ u,
    float* __restrict__ out,
    int N)  // N = B*4 nodes
{
    const int t = threadIdx.x;
    const int base = blockIdx.x * (256 * NELEM) + t;
    const int node = t & 3;  // stride-256 elements keep the same node id

    // Goal targets per node: (2,2), (-2,2), (-2,-2), (2,-2)
    const float xt = (node == 1 || node == 2) ? -2.f : 2.f;
    const float yt = (node >= 2) ? -2.f : 2.f;

    const float4* x4 = reinterpret_cast<const float4*>(x);
    const float2* u2 = reinterpret_cast<const float2*>(u);
    float4*       o4 = reinterpret_cast<float4*>(out);

    float4 s[NELEM];
    float2 uc[NELEM];
    bool   ok[NELEM];

#pragma unroll
    for (int e = 0; e < NELEM; ++e) {
        int g = base + e * 256;
        ok[e] = (g < N);     // N % 4 == 0 -> quads never straddle the edge
        if (ok[e]) {
            s[e]  = x4[g];
            uc[e] = u2[g];
        }
    }

#pragma unroll
    for (int e = 0; e < NELEM; ++e) {
        float px = s[e].x, py = s[e].y, vx = s[e].z, vy = s[e].w;

        float ax = -(px - xt) - 2.f * vx;
        float ay = -(py - yt) - 2.f * vy;

        // Neighbor positions via DPP quad_perm (lane ^ 1, ^2, ^3)
        edge(px, py, qp<0xB1>(px), qp<0xB1>(py), 4.0f,          ax, ay);
        edge(px, py, qp<0x4E>(px), qp<0x4E>(py), 4.2720018727f, ax, ay); // sqrt(18.25)
        edge(px, py, qp<0x1B>(px), qp<0x1B>(py), 1.5f,          ax, ay);

        float4 r;
        r.x = fmaf(TS, vx, px);
        r.y = fmaf(TS, vy, py);
        r.z = fmaf(TS, ax + uc[e].x, vx);
        r.w = fmaf(TS, ay + uc[e].y, vy);

        if (ok[e]) {
            int g = base + e * 256;
            o4[g] = r;
        }
    }
}

extern "C" void kernel_launch(void* const* d_in, const int* in_sizes, int n_in,
                              void* d_out, int out_size, void* d_ws, size_t ws_size,
                              hipStream_t stream) {
    // Inputs (setup_inputs order): t (scalar), x (B*16 f32), u (B*8 f32),
    // w (16 f32, unused), xbar (16 f32, fixed constant baked in).
    const float* x = (const float*)d_in[1];
    const float* u = (const float*)d_in[2];
    float* out = (float*)d_out;

    int N = in_sizes[1] / 4;  // nodes = B*4
    int per_block = 256 * NELEM;
    int grid = (N + per_block - 1) / per_block;
    springs_node_kernel<<<grid, 256, 0, stream>>>(x, u, out, N);
}